// Round 1
// baseline (811.361 us; speedup 1.0000x reference)
//
#include <hip/hip_runtime.h>

static constexpr int NBATCH = 32;   // B
static constexpr int NDIM   = 32;   // D
static constexpr int NSEQ   = 8192; // S
static constexpr int NFEAT  = 128;  // F

// ---------------------------------------------------------------------------
// K0: M[h][g] = sum_f Wq[f*128+h] * Wk[f*128+g]   (M = Wq^T @ Wk)
// ---------------------------------------------------------------------------
__global__ __launch_bounds__(256) void k_mw(const float* __restrict__ Wq,
                                            const float* __restrict__ Wk,
                                            float* __restrict__ M) {
  int tid = blockIdx.x * 256 + threadIdx.x;   // 16384 total
  int h = tid >> 7, g = tid & 127;
  float acc = 0.f;
#pragma unroll 16
  for (int f = 0; f < NFEAT; ++f)
    acc = fmaf(Wq[f * NFEAT + h], Wk[f * NFEAT + g], acc);
  M[tid] = acc;
}

// ---------------------------------------------------------------------------
// K1: qm = query @ M   -> writes into `out` (used as scratch)
// 256 threads, 8 rows x 8 cols per thread, 128-row blocks.
// LDS: Ms[128*128] + Qb[128*132] (pad 132 -> conflict-free A reads), dynamic.
// Next block prefetched into registers (st[16]) during compute.
// ---------------------------------------------------------------------------
__global__ __launch_bounds__(256, 1) void k_qm(const float* __restrict__ Q,
                                               const float* __restrict__ Mg,
                                               float* __restrict__ out) {
  extern __shared__ float sm[];
  float* Ms = sm;            // 128*128
  float* Qb = sm + 16384;    // 128*132
  const int t = threadIdx.x;
  const int rq = t >> 4;     // 0..15
  const int fg = t & 15;     // 0..15
  const int c0 = fg * 4, c1 = 64 + fg * 4;  // 4+4 column split: bank-uniform

  // load M straight (row-major, no pad; reads below are 2-way -> free)
#pragma unroll
  for (int k = 0; k < 16; ++k) {
    int e = t * 4 + k * 1024;
    *(float4*)&Ms[e] = *(const float4*)&Mg[e];
  }

  float4 st[16];
  int blk = blockIdx.x;
  {
    const float* src = Q + (size_t)blk * (128 * NFEAT);
#pragma unroll
    for (int k = 0; k < 16; ++k) st[k] = *(const float4*)&src[t * 4 + k * 1024];
  }
  const int NITER = (NBATCH * NSEQ / 128) / 256;  // 2048 blocks / 256 WGs = 8
  for (int it = 0; it < NITER; ++it) {
    __syncthreads();
#pragma unroll
    for (int k = 0; k < 16; ++k) {
      int e = t * 4 + k * 1024;
      *(float4*)&Qb[(e >> 7) * 132 + (e & 127)] = st[k];
    }
    __syncthreads();
    int nblk = blk + gridDim.x;
    if (it + 1 < NITER) {   // prefetch next block into regs (hidden by compute)
      const float* src = Q + (size_t)nblk * (128 * NFEAT);
#pragma unroll
      for (int k = 0; k < 16; ++k) st[k] = *(const float4*)&src[t * 4 + k * 1024];
    }

    float acc[8][8];
#pragma unroll
    for (int m = 0; m < 8; ++m)
#pragma unroll
      for (int c = 0; c < 8; ++c) acc[m][c] = 0.f;

    for (int h = 0; h < 128; h += 4) {
      float4 a[8];
#pragma unroll
      for (int m = 0; m < 8; ++m)
        a[m] = *(const float4*)&Qb[(rq + 16 * m) * 132 + h];
#pragma unroll
      for (int hh = 0; hh < 4; ++hh) {
        float4 b0 = *(const float4*)&Ms[(h + hh) * 128 + c0];
        float4 b1 = *(const float4*)&Ms[(h + hh) * 128 + c1];
#pragma unroll
        for (int m = 0; m < 8; ++m) {
          float av = (&a[m].x)[hh];
          acc[m][0] = fmaf(av, b0.x, acc[m][0]);
          acc[m][1] = fmaf(av, b0.y, acc[m][1]);
          acc[m][2] = fmaf(av, b0.z, acc[m][2]);
          acc[m][3] = fmaf(av, b0.w, acc[m][3]);
          acc[m][4] = fmaf(av, b1.x, acc[m][4]);
          acc[m][5] = fmaf(av, b1.y, acc[m][5]);
          acc[m][6] = fmaf(av, b1.z, acc[m][6]);
          acc[m][7] = fmaf(av, b1.w, acc[m][7]);
        }
      }
    }

    float* dst = out + (size_t)blk * (128 * NFEAT);
#pragma unroll
    for (int m = 0; m < 8; ++m) {
      int r = rq + 16 * m;
      float4 o0 = {acc[m][0], acc[m][1], acc[m][2], acc[m][3]};
      float4 o1 = {acc[m][4], acc[m][5], acc[m][6], acc[m][7]};
      *(float4*)&dst[r * NFEAT + c0] = o0;
      *(float4*)&dst[r * NFEAT + c1] = o1;
    }
    blk = nblk;
  }
}

// ---------------------------------------------------------------------------
// K2: per position i: scores = qm . K^T (scaled), softmax over d, ov = attn . V
// qm read from QOV (d_out), ov written back IN-PLACE (same rows, after reads).
// 256 threads, 16 positions per WG, next position prefetched into registers.
// ---------------------------------------------------------------------------
__global__ __launch_bounds__(256, 2) void k_attn(const float* __restrict__ Kg,
                                                 const float* __restrict__ Vg,
                                                 float* __restrict__ QOV) {
  __shared__ float qmL[32 * 132];
  __shared__ float KL[32 * 132];
  __shared__ float VL[32 * 132];
  __shared__ float aL[32 * 36];
  const int t = threadIdx.x;
  const int row = t >> 3, q8 = t & 7;        // staging map
  const int bg = t >> 4, dg = t & 15;        // compute map
  const int c0 = dg * 4, c1 = 64 + dg * 4;   // GEMM3 column split
  const int NP = 16;
  int p = blockIdx.x * NP;

  float4 stq[4], stk[4], stv[4];
  {
    const float* qs = QOV + ((size_t)row * NSEQ + p) * NFEAT;
    const float* ks = Kg + ((size_t)row * NSEQ + p) * NFEAT;
    const float* vs = Vg + ((size_t)row * NSEQ + p) * NFEAT;
#pragma unroll
    for (int j = 0; j < 4; ++j) {
      int c = j * 32 + q8 * 4;
      stq[j] = *(const float4*)&qs[c];
      stk[j] = *(const float4*)&ks[c];
      stv[j] = *(const float4*)&vs[c];
    }
  }

  for (int it = 0; it < NP; ++it, ++p) {
    __syncthreads();
#pragma unroll
    for (int j = 0; j < 4; ++j) {
      int c = j * 32 + q8 * 4;
      *(float4*)&qmL[row * 132 + c] = stq[j];
      *(float4*)&KL[row * 132 + c] = stk[j];
      *(float4*)&VL[row * 132 + c] = stv[j];
    }
    __syncthreads();
    if (it + 1 < NP) {   // prefetch next position (within this WG's range)
      const float* qs = QOV + ((size_t)row * NSEQ + (p + 1)) * NFEAT;
      const float* ks = Kg + ((size_t)row * NSEQ + (p + 1)) * NFEAT;
      const float* vs = Vg + ((size_t)row * NSEQ + (p + 1)) * NFEAT;
#pragma unroll
      for (int j = 0; j < 4; ++j) {
        int c = j * 32 + q8 * 4;
        stq[j] = *(const float4*)&qs[c];
        stk[j] = *(const float4*)&ks[c];
        stv[j] = *(const float4*)&vs[c];
      }
    }

    // GEMM2: scores[b,d] for b in {bg,bg+16}, d in {dg,dg+16}
    float s00 = 0.f, s01 = 0.f, s10 = 0.f, s11 = 0.f;
    for (int g = 0; g < 128; g += 4) {
      float4 qa = *(const float4*)&qmL[bg * 132 + g];
      float4 qb = *(const float4*)&qmL[(bg + 16) * 132 + g];
      float4 ka = *(const float4*)&KL[dg * 132 + g];
      float4 kb = *(const float4*)&KL[(dg + 16) * 132 + g];
      s00 = fmaf(qa.x, ka.x, s00); s00 = fmaf(qa.y, ka.y, s00);
      s00 = fmaf(qa.z, ka.z, s00); s00 = fmaf(qa.w, ka.w, s00);
      s01 = fmaf(qa.x, kb.x, s01); s01 = fmaf(qa.y, kb.y, s01);
      s01 = fmaf(qa.z, kb.z, s01); s01 = fmaf(qa.w, kb.w, s01);
      s10 = fmaf(qb.x, ka.x, s10); s10 = fmaf(qb.y, ka.y, s10);
      s10 = fmaf(qb.z, ka.z, s10); s10 = fmaf(qb.w, ka.w, s10);
      s11 = fmaf(qb.x, kb.x, s11); s11 = fmaf(qb.y, kb.y, s11);
      s11 = fmaf(qb.z, kb.z, s11); s11 = fmaf(qb.w, kb.w, s11);
    }
    const float sc = 0.08838834764831845f;  // 1/sqrt(128)
    s00 *= sc; s01 *= sc; s10 *= sc; s11 *= sc;

    // softmax over d (32 values per b-row, spread across 16 lanes x 2 regs)
    float m0 = fmaxf(s00, s01), m1 = fmaxf(s10, s11);
#pragma unroll
    for (int o = 1; o < 16; o <<= 1) {
      m0 = fmaxf(m0, __shfl_xor(m0, o));
      m1 = fmaxf(m1, __shfl_xor(m1, o));
    }
    float p00 = __expf(s00 - m0), p01 = __expf(s01 - m0);
    float p10 = __expf(s10 - m1), p11 = __expf(s11 - m1);
    float l0 = p00 + p01, l1 = p10 + p11;
#pragma unroll
    for (int o = 1; o < 16; o <<= 1) {
      l0 += __shfl_xor(l0, o);
      l1 += __shfl_xor(l1, o);
    }
    float r0 = 1.f / l0, r1 = 1.f / l1;
    aL[bg * 36 + dg]          = p00 * r0;
    aL[bg * 36 + 16 + dg]     = p01 * r0;
    aL[(bg + 16) * 36 + dg]      = p10 * r1;
    aL[(bg + 16) * 36 + 16 + dg] = p11 * r1;
    __syncthreads();

    // GEMM3: ov[b,h] = sum_d attn[b,d] * V[d,h]
    float ov[2][8];
#pragma unroll
    for (int m = 0; m < 2; ++m)
#pragma unroll
      for (int c = 0; c < 8; ++c) ov[m][c] = 0.f;
    for (int d = 0; d < 32; d += 4) {
      float4 a0 = *(const float4*)&aL[bg * 36 + d];
      float4 a1 = *(const float4*)&aL[(bg + 16) * 36 + d];
#pragma unroll
      for (int dd = 0; dd < 4; ++dd) {
        float4 v0 = *(const float4*)&VL[(d + dd) * 132 + c0];
        float4 v1 = *(const float4*)&VL[(d + dd) * 132 + c1];
        float w0 = (&a0.x)[dd], w1 = (&a1.x)[dd];
        ov[0][0] = fmaf(w0, v0.x, ov[0][0]); ov[0][1] = fmaf(w0, v0.y, ov[0][1]);
        ov[0][2] = fmaf(w0, v0.z, ov[0][2]); ov[0][3] = fmaf(w0, v0.w, ov[0][3]);
        ov[0][4] = fmaf(w0, v1.x, ov[0][4]); ov[0][5] = fmaf(w0, v1.y, ov[0][5]);
        ov[0][6] = fmaf(w0, v1.z, ov[0][6]); ov[0][7] = fmaf(w0, v1.w, ov[0][7]);
        ov[1][0] = fmaf(w1, v0.x, ov[1][0]); ov[1][1] = fmaf(w1, v0.y, ov[1][1]);
        ov[1][2] = fmaf(w1, v0.z, ov[1][2]); ov[1][3] = fmaf(w1, v0.w, ov[1][3]);
        ov[1][4] = fmaf(w1, v1.x, ov[1][4]); ov[1][5] = fmaf(w1, v1.y, ov[1][5]);
        ov[1][6] = fmaf(w1, v1.z, ov[1][6]); ov[1][7] = fmaf(w1, v1.w, ov[1][7]);
      }
    }
    size_t b0 = ((size_t)bg * NSEQ + p) * NFEAT;
    size_t b1 = ((size_t)(bg + 16) * NSEQ + p) * NFEAT;
    float4 o00 = {ov[0][0], ov[0][1], ov[0][2], ov[0][3]};
    float4 o01 = {ov[0][4], ov[0][5], ov[0][6], ov[0][7]};
    float4 o10 = {ov[1][0], ov[1][1], ov[1][2], ov[1][3]};
    float4 o11 = {ov[1][4], ov[1][5], ov[1][6], ov[1][7]};
    *(float4*)&QOV[b0 + c0] = o00;
    *(float4*)&QOV[b0 + c1] = o01;
    *(float4*)&QOV[b1 + c0] = o10;
    *(float4*)&QOV[b1 + c1] = o11;
  }
}

// ---------------------------------------------------------------------------
// K3: proj = ov @ Wv^T, in-place on OV (=d_out). Same skeleton as k_qm,
// B-operand staged transposed into padded LDS (WT[h][f] = Wv[f][h]).
// ---------------------------------------------------------------------------
__global__ __launch_bounds__(256, 1) void k_proj(float* __restrict__ OV,
                                                 const float* __restrict__ Wv) {
  extern __shared__ float sm[];
  float* WT = sm;                 // 128*132
  float* Ab = sm + 128 * 132;     // 128*132
  const int t = threadIdx.x;
  const int rq = t >> 4, fg = t & 15;
  const int c0 = fg * 4, c1 = 64 + fg * 4;

  // transpose-stage Wv (once per WG; bank conflicts here are amortized away)
#pragma unroll
  for (int k = 0; k < 16; ++k) {
    int e = t * 4 + k * 1024;
    int f = e >> 7, h = e & 127;
    float4 w = *(const float4*)&Wv[e];
    WT[(h + 0) * 132 + f] = w.x;
    WT[(h + 1) * 132 + f] = w.y;
    WT[(h + 2) * 132 + f] = w.z;
    WT[(h + 3) * 132 + f] = w.w;
  }

  float4 st[16];
  int blk = blockIdx.x;
  {
    const float* src = OV + (size_t)blk * (128 * NFEAT);
#pragma unroll
    for (int k = 0; k < 16; ++k) st[k] = *(const float4*)&src[t * 4 + k * 1024];
  }
  const int NITER = (NBATCH * NSEQ / 128) / 256;  // 8
  for (int it = 0; it < NITER; ++it) {
    __syncthreads();
#pragma unroll
    for (int k = 0; k < 16; ++k) {
      int e = t * 4 + k * 1024;
      *(float4*)&Ab[(e >> 7) * 132 + (e & 127)] = st[k];
    }
    __syncthreads();
    int nblk = blk + gridDim.x;
    if (it + 1 < NITER) {
      const float* src = OV + (size_t)nblk * (128 * NFEAT);
#pragma unroll
      for (int k = 0; k < 16; ++k) st[k] = *(const float4*)&src[t * 4 + k * 1024];
    }

    float acc[8][8];
#pragma unroll
    for (int m = 0; m < 8; ++m)
#pragma unroll
      for (int c = 0; c < 8; ++c) acc[m][c] = 0.f;

    for (int h = 0; h < 128; h += 4) {
      float4 a[8];
#pragma unroll
      for (int m = 0; m < 8; ++m)
        a[m] = *(const float4*)&Ab[(rq + 16 * m) * 132 + h];
#pragma unroll
      for (int hh = 0; hh < 4; ++hh) {
        float4 b0 = *(const float4*)&WT[(h + hh) * 132 + c0];
        float4 b1 = *(const float4*)&WT[(h + hh) * 132 + c1];
#pragma unroll
        for (int m = 0; m < 8; ++m) {
          float av = (&a[m].x)[hh];
          acc[m][0] = fmaf(av, b0.x, acc[m][0]);
          acc[m][1] = fmaf(av, b0.y, acc[m][1]);
          acc[m][2] = fmaf(av, b0.z, acc[m][2]);
          acc[m][3] = fmaf(av, b0.w, acc[m][3]);
          acc[m][4] = fmaf(av, b1.x, acc[m][4]);
          acc[m][5] = fmaf(av, b1.y, acc[m][5]);
          acc[m][6] = fmaf(av, b1.z, acc[m][6]);
          acc[m][7] = fmaf(av, b1.w, acc[m][7]);
        }
      }
    }

    float* dst = OV + (size_t)blk * (128 * NFEAT);
#pragma unroll
    for (int m = 0; m < 8; ++m) {
      int r = rq + 16 * m;
      float4 o0 = {acc[m][0], acc[m][1], acc[m][2], acc[m][3]};
      float4 o1 = {acc[m][4], acc[m][5], acc[m][6], acc[m][7]};
      *(float4*)&dst[r * NFEAT + c0] = o0;
      *(float4*)&dst[r * NFEAT + c1] = o1;
    }
    blk = nblk;
  }
}

// ---------------------------------------------------------------------------
extern "C" void kernel_launch(void* const* d_in, const int* in_sizes, int n_in,
                              void* d_out, int out_size, void* d_ws, size_t ws_size,
                              hipStream_t stream) {
  const float* Q  = (const float*)d_in[0];
  const float* K  = (const float*)d_in[1];
  const float* V  = (const float*)d_in[2];
  const float* Wq = (const float*)d_in[3];
  const float* Wk = (const float*)d_in[4];
  const float* Wv = (const float*)d_in[5];
  float* out = (float*)d_out;
  float* Mws = (float*)d_ws;   // 128*128 floats = 64 KB

  const int lds_qm   = (16384 + 128 * 132) * 4;      // 133120 B
  const int lds_proj = (2 * 128 * 132) * 4;          // 135168 B
  hipFuncSetAttribute(reinterpret_cast<const void*>(k_qm),
                      hipFuncAttributeMaxDynamicSharedMemorySize, lds_qm);
  hipFuncSetAttribute(reinterpret_cast<const void*>(k_proj),
                      hipFuncAttributeMaxDynamicSharedMemorySize, lds_proj);

  k_mw<<<64, 256, 0, stream>>>(Wq, Wk, Mws);
  k_qm<<<256, 256, lds_qm, stream>>>(Q, Mws, out);
  k_attn<<<512, 256, 0, stream>>>(K, V, out);
  k_proj<<<256, 256, lds_proj, stream>>>(out, Wv);
}